// Round 3
// baseline (1000.818 us; speedup 1.0000x reference)
//
#include <hip/hip_runtime.h>

#define N_EMB  65536
#define DIM    512
#define K_C    256
#define NCHUNK (DIM / 32)   // 16 k-chunks of 32
#define M_BLK  64           // rows per block (4 m-tiles of 16)

typedef _Float16 half8 __attribute__((ext_vector_type(8)));
typedef _Float16 half4 __attribute__((ext_vector_type(4)));
typedef float    f32x4 __attribute__((ext_vector_type(4)));

#define B_FRAGS (NCHUNK * 16 * 64)

// ---- Prologue 1: centroids -> f16 hi/lo B-fragments ----
// B[k][n] = cent[n][k]. Fragment (chunk c, ntile nt): lane l holds
// B[k = c*32 + (l>>4)*8 + j][n = nt*16 + (l&15)], j=0..7.
__global__ void conv_B(const float* __restrict__ cent,
                       half8* __restrict__ Bhi, half8* __restrict__ Blo) {
    const int c = blockIdx.x;
    const int tid = threadIdx.x;
    for (int i = 0; i < 4; ++i) {
        const int u  = tid + 256 * i;
        const int nt = u >> 6;
        const int l  = u & 63;
        const int n  = nt * 16 + (l & 15);
        const int k0 = c * 32 + (l >> 4) * 8;
        const float* src = cent + (size_t)n * DIM + k0;
        half8 h, lo;
        #pragma unroll
        for (int j = 0; j < 8; ++j) {
            const float v = src[j];
            const _Float16 hv = (_Float16)v;
            h[j]  = hv;
            lo[j] = (_Float16)(v - (float)hv);
        }
        const int idx = (c * 16 + nt) * 64 + l;
        Bhi[idx] = h;
        Blo[idx] = lo;
    }
}

// ---- Prologue 2: centroid norms (fp32) — identical to round-1 values ----
__global__ void centroid_norms(const float* __restrict__ cent,
                               float* __restrict__ cnorm) {
    const int k = blockIdx.x;
    const int lane = threadIdx.x;  // 64
    const float4* row = (const float4*)(cent + (size_t)k * DIM);
    float s = 0.f;
    for (int i = lane; i < DIM / 4; i += 64) {
        float4 v = row[i];
        s += v.x * v.x + v.y * v.y + v.z * v.z + v.w * v.w;
    }
    #pragma unroll
    for (int off = 32; off > 0; off >>= 1) s += __shfl_down(s, off, 64);
    if (lane == 0) cnorm[k] = s;
}

__device__ __forceinline__ void ins3(float s, int col,
                                     float& v1, int& i1, float& v2, int& i2,
                                     float& v3, int& i3) {
    if (s < v1 || (s == v1 && col < i1)) {
        v3 = v2; i3 = i2; v2 = v1; i2 = i1; v1 = s; i1 = col;
    } else if (s < v2 || (s == v2 && col < i2)) {
        v3 = v2; i3 = i2; v2 = s; i2 = col;
    } else if (s < v3 || (s == v3 && col < i3)) {
        v3 = s; i3 = col;
    }
}

// ---- Main: MFMA approx scores -> per-wave top-3 -> exact fp32 rescore ----
__global__ __launch_bounds__(256)
void neg_main(const float* __restrict__ emb,
              const float* __restrict__ cent,
              const half8* __restrict__ Bhi,
              const half8* __restrict__ Blo,
              const float* __restrict__ cnorm,
              float* __restrict__ out) {
    __shared__ half8 Ahi[4 * 64];
    __shared__ half8 Alo[4 * 64];
    __shared__ unsigned int cand[M_BLK][4][6];  // per-row per-wave {v,i}x3
    __shared__ float exsc[M_BLK][12];
    __shared__ int sidx[M_BLK];

    const int tid  = threadIdx.x;
    const int w    = tid >> 6;
    const int lane = tid & 63;
    const int row0 = blockIdx.x * M_BLK;

    f32x4 acc[4][4];
    #pragma unroll
    for (int a = 0; a < 4; ++a)
        #pragma unroll
        for (int b = 0; b < 4; ++b)
            acc[a][b] = (f32x4)0.f;

    for (int c = 0; c < NCHUNK; ++c) {
        #pragma unroll
        for (int i = 0; i < 2; ++i) {
            const int u   = tid + 256 * i;
            const int row = u >> 3;
            const int kq  = u & 7;
            const float4 v = *(const float4*)(emb + (size_t)(row0 + row) * DIM
                                              + c * 32 + kq * 4);
            half4 hv, lv;
            hv.x = (_Float16)v.x; lv.x = (_Float16)(v.x - (float)hv.x);
            hv.y = (_Float16)v.y; lv.y = (_Float16)(v.y - (float)hv.y);
            hv.z = (_Float16)v.z; lv.z = (_Float16)(v.z - (float)hv.z);
            hv.w = (_Float16)v.w; lv.w = (_Float16)(v.w - (float)hv.w);
            const int mt = row >> 4;
            const int q  = kq >> 1;
            const int l  = (row & 15) | (q << 4);
            const int off8 = (kq & 1);
            *((half4*)((char*)&Ahi[mt * 64 + l] + off8 * 8)) = hv;
            *((half4*)((char*)&Alo[mt * 64 + l] + off8 * 8)) = lv;
        }
        __syncthreads();

        half8 ah[4], al[4], bh[4], bl[4];
        #pragma unroll
        for (int mt = 0; mt < 4; ++mt) {
            ah[mt] = Ahi[mt * 64 + lane];
            al[mt] = Alo[mt * 64 + lane];
        }
        #pragma unroll
        for (int i = 0; i < 4; ++i) {
            const int idx = (c * 16 + (w * 4 + i)) * 64 + lane;
            bh[i] = Bhi[idx];
            bl[i] = Blo[idx];
        }
        #pragma unroll
        for (int mt = 0; mt < 4; ++mt)
            #pragma unroll
            for (int i = 0; i < 4; ++i) {
                acc[mt][i] = __builtin_amdgcn_mfma_f32_16x16x32_f16(ah[mt], bh[i], acc[mt][i], 0, 0, 0);
                acc[mt][i] = __builtin_amdgcn_mfma_f32_16x16x32_f16(ah[mt], bl[i], acc[mt][i], 0, 0, 0);
                acc[mt][i] = __builtin_amdgcn_mfma_f32_16x16x32_f16(al[mt], bh[i], acc[mt][i], 0, 0, 0);
            }
        __syncthreads();
    }

    // ---- approx scores + per-wave top-3 (16-lane butterfly per row) ----
    float cn[4];
    #pragma unroll
    for (int i = 0; i < 4; ++i) cn[i] = cnorm[w * 64 + i * 16 + (lane & 15)];

    #pragma unroll
    for (int mt = 0; mt < 4; ++mt) {
        #pragma unroll
        for (int r = 0; r < 4; ++r) {
            float v1 = 1e30f, v2 = 1e30f, v3 = 1e30f;
            int i1 = 0x7fffffff, i2 = 0x7fffffff, i3 = 0x7fffffff;
            #pragma unroll
            for (int i = 0; i < 4; ++i) {
                const float s = fmaf(-2.f, acc[mt][i][r], cn[i]);
                const int col = w * 64 + i * 16 + (lane & 15);
                ins3(s, col, v1, i1, v2, i2, v3, i3);
            }
            #pragma unroll
            for (int off = 1; off < 16; off <<= 1) {
                const float ov1 = __shfl_xor(v1, off, 64);
                const int   oi1 = __shfl_xor(i1, off, 64);
                const float ov2 = __shfl_xor(v2, off, 64);
                const int   oi2 = __shfl_xor(i2, off, 64);
                const float ov3 = __shfl_xor(v3, off, 64);
                const int   oi3 = __shfl_xor(i3, off, 64);
                ins3(ov1, oi1, v1, i1, v2, i2, v3, i3);
                ins3(ov2, oi2, v1, i1, v2, i2, v3, i3);
                ins3(ov3, oi3, v1, i1, v2, i2, v3, i3);
            }
            if ((lane & 15) == 0) {
                const int row = mt * 16 + (lane >> 4) * 4 + r;
                cand[row][w][0] = (unsigned int)i1;
                cand[row][w][1] = (unsigned int)i2;
                cand[row][w][2] = (unsigned int)i3;
            }
        }
    }
    __syncthreads();

    // ---- exact fp32 rescore of 12 candidates/row (round-1 arithmetic) ----
    for (int k = 0; k < 3; ++k) {
        const int t    = tid + 256 * k;   // 0..767
        const int row  = t / 12;
        const int j    = t % 12;
        const int ww   = j >> 2;          // wait: 12 = 4 waves * 3 slots
        const int ci   = (int)cand[row][j / 3][j % 3];
        (void)ww;
        const float* ep = emb + (size_t)(row0 + row) * DIM;
        const float* cp = cent + (size_t)ci * DIM;
        float dot = 0.f;
        for (int d = 0; d < DIM; d += 4) {
            const float4 e4 = *(const float4*)(ep + d);
            const float4 c4 = *(const float4*)(cp + d);
            dot = fmaf(e4.x, c4.x, dot);
            dot = fmaf(e4.y, c4.y, dot);
            dot = fmaf(e4.z, c4.z, dot);
            dot = fmaf(e4.w, c4.w, dot);
        }
        exsc[row][j] = fmaf(-2.f, dot, cnorm[ci]);
    }
    __syncthreads();

    // ---- exact top-2 selection per row ----
    if (tid < M_BLK) {
        float v1 = 1e30f, v2 = 1e30f;
        int i1 = 0x7fffffff, i2 = 0x7fffffff;
        #pragma unroll
        for (int j = 0; j < 12; ++j) {
            const int ci  = (int)cand[tid][j / 3][j % 3];
            const float s = exsc[tid][j];
            if (s < v1 || (s == v1 && ci < i1)) { v2 = v1; i2 = i1; v1 = s; i1 = ci; }
            else if (s < v2 || (s == v2 && ci < i2)) { v2 = s; i2 = ci; }
        }
        sidx[tid] = i2;
    }
    __syncthreads();

    // ---- gather: out[row0+m] = centroids[sidx[m]] ----
    for (int i = tid; i < M_BLK * (DIM / 4); i += 256) {
        const int m   = i >> 7;
        const int off = i & 127;
        const int cix = sidx[m];
        ((float4*)(out + (size_t)(row0 + m) * DIM))[off] =
            ((const float4*)(cent + (size_t)cix * DIM))[off];
    }
}

extern "C" void kernel_launch(void* const* d_in, const int* in_sizes, int n_in,
                              void* d_out, int out_size, void* d_ws, size_t ws_size,
                              hipStream_t stream) {
    const float* emb  = (const float*)d_in[0];
    const float* cent = (const float*)d_in[1];

    half8* Bhi  = (half8*)d_ws;
    half8* Blo  = (half8*)((char*)d_ws + (size_t)B_FRAGS * 16);
    float* cnorm = (float*)((char*)d_ws + (size_t)B_FRAGS * 32);

    conv_B<<<NCHUNK, 256, 0, stream>>>(cent, Bhi, Blo);
    centroid_norms<<<K_C, 64, 0, stream>>>(cent, cnorm);
    neg_main<<<N_EMB / M_BLK, 256, 0, stream>>>(emb, cent, Bhi, Blo, cnorm,
                                                (float*)d_out);
}